// Round 2
// baseline (556.901 us; speedup 1.0000x reference)
//
#include <hip/hip_runtime.h>

#define BB 4
#define CC 64
#define HH 256
#define WW 256
#define KK 9
#define NOFF 18
#define HO 254
#define WO 254
#define TS 16           // output tile side
#define TP (TS + 2)     // staged patch side (tile + 2 halo)
#define CH 8            // channels staged per LDS stage
#define PADW 19         // padded LDS row stride

__global__ __launch_bounds__(256) void deform_fused_kernel(
    const float* __restrict__ x,
    const float* __restrict__ offset_w,
    const float* __restrict__ offset_b,
    const float* __restrict__ deform_w,
    const float* __restrict__ deform_b,
    float* __restrict__ out)
{
    __shared__ float s_tile[CH][TP][PADW];   // 8 * 18 * 19 * 4 = 10.9 KB
    __shared__ float s_dw[CC * KK];          // 2.3 KB, broadcast reads

    const int tx = threadIdx.x & 15;
    const int ty = threadIdx.x >> 4;
    const int x0 = blockIdx.x * TS;
    const int y0 = blockIdx.y * TS;
    const int b  = blockIdx.z;
    const int ho = y0 + ty;
    const int wo = x0 + tx;
    const bool valid = (ho < HO) && (wo < WO);

    for (int i = threadIdx.x; i < CC * KK; i += 256) s_dw[i] = deform_w[i];

    const float* xb = x + (size_t)b * CC * HH * WW;

    // ---------- step 1: offset conv (valid 3x3, 18 out channels) ----------
    float accO[NOFF];
    #pragma unroll
    for (int o = 0; o < NOFF; ++o) accO[o] = offset_b[o];   // uniform -> s_load

    for (int c0 = 0; c0 < CC; c0 += CH) {
        __syncthreads();   // protect previous stage's tile reads (and s_dw on iter 0)
        // stage CH channel patches (18x18 each) into LDS
        for (int i = threadIdx.x; i < CH * TP * TP; i += 256) {
            int cc  = i / (TP * TP);
            int rem = i - cc * (TP * TP);
            int r   = rem / TP;
            int col = rem - r * TP;
            int gy = y0 + r;
            int gx = x0 + col;
            float v = 0.0f;
            if (gy < HH && gx < WW)
                v = xb[(size_t)(c0 + cc) * (HH * WW) + gy * WW + gx];
            s_tile[cc][r][col] = v;
        }
        __syncthreads();

        #pragma unroll
        for (int cc = 0; cc < CH; ++cc) {
            float xv[9];
            #pragma unroll
            for (int kh = 0; kh < 3; ++kh)
                #pragma unroll
                for (int kw = 0; kw < 3; ++kw)
                    xv[kh * 3 + kw] = s_tile[cc][ty + kh][tx + kw];

            // weights via wave-uniform scalar loads, folded as SGPR FMA operand
            const float* wc = offset_w + (size_t)(c0 + cc) * KK;
            #pragma unroll
            for (int o = 0; o < NOFF; ++o) {
                #pragma unroll
                for (int t = 0; t < KK; ++t)
                    accO[o] = fmaf(xv[t], wc[o * (CC * KK) + t], accO[o]);
            }
        }
    }

    if (!valid) return;   // no barriers below this point

    // ---------- step 2: deformable bilinear gather + dot ----------
    float acc = deform_b[0];

    #pragma unroll
    for (int k = 0; k < KK; ++k) {
        const int kh = k / 3;
        const int kw = k % 3;
        float dy = accO[2 * k];
        float dx = accO[2 * k + 1];
        float py = (float)(ho + kh) + dy;
        float px = (float)(wo + kw) + dx;

        float y0f = floorf(py);
        float x0f = floorf(px);
        float ly = py - y0f;
        float lx = px - x0f;
        int yi0 = (int)y0f, xi0 = (int)x0f;
        int yi1 = yi0 + 1,  xi1 = xi0 + 1;

        float w00 = (1.0f - ly) * (1.0f - lx);
        float w01 = (1.0f - ly) * lx;
        float w10 = ly * (1.0f - lx);
        float w11 = ly * lx;
        if (!(yi0 >= 0 && yi0 < HH && xi0 >= 0 && xi0 < WW)) w00 = 0.0f;
        if (!(yi0 >= 0 && yi0 < HH && xi1 >= 0 && xi1 < WW)) w01 = 0.0f;
        if (!(yi1 >= 0 && yi1 < HH && xi0 >= 0 && xi0 < WW)) w10 = 0.0f;
        if (!(yi1 >= 0 && yi1 < HH && xi1 >= 0 && xi1 < WW)) w11 = 0.0f;

        int y0c = min(max(yi0, 0), HH - 1);
        int y1c = min(max(yi1, 0), HH - 1);
        int x0c = min(max(xi0, 0), WW - 1);
        int x1c = min(max(xi1, 0), WW - 1);
        int i00 = y0c * WW + x0c;
        int i01 = y0c * WW + x1c;
        int i10 = y1c * WW + x0c;
        int i11 = y1c * WW + x1c;

        for (int c = 0; c < CC; ++c) {
            const float* xc = xb + (size_t)c * (HH * WW);
            float g = w00 * xc[i00] + w01 * xc[i01] + w10 * xc[i10] + w11 * xc[i11];
            acc = fmaf(g, s_dw[c * KK + k], acc);
        }
    }

    out[(size_t)b * (HO * WO) + ho * WO + wo] = acc;
}

extern "C" void kernel_launch(void* const* d_in, const int* in_sizes, int n_in,
                              void* d_out, int out_size, void* d_ws, size_t ws_size,
                              hipStream_t stream) {
    const float* x        = (const float*)d_in[0];
    const float* offset_w = (const float*)d_in[1];
    const float* offset_b = (const float*)d_in[2];
    const float* deform_w = (const float*)d_in[3];
    const float* deform_b = (const float*)d_in[4];
    float* out = (float*)d_out;

    dim3 block(256);
    dim3 grid((WO + TS - 1) / TS, (HO + TS - 1) / TS, BB);  // 16 x 16 x 4
    hipLaunchKernelGGL(deform_fused_kernel, grid, block, 0, stream,
                       x, offset_w, offset_b, deform_w, deform_b, out);
}

// Round 3
// 508.026 us; speedup vs baseline: 1.0962x; 1.0962x over previous
//
#include <hip/hip_runtime.h>

#define BB 4
#define CC 64
#define HH 256
#define WW 256
#define KK 9
#define NOFF 18
#define HO 254
#define WO 254
#define TS 16           // output tile side
#define S  2            // offset slack (|dy|,|dx| <= 2 covered in LDS fast path)
#define PT 22           // staged patch side: TS + 2 (kernel) + 2*S
#define PSTR 23         // padded LDS row stride
#define CH 8            // channels staged per stage

__global__ __launch_bounds__(256) void deform_fused_kernel(
    const float* __restrict__ x,
    const float* __restrict__ offset_w,
    const float* __restrict__ offset_b,
    const float* __restrict__ deform_w,
    const float* __restrict__ deform_b,
    float* __restrict__ out)
{
    __shared__ float s_x[CH][PT][PSTR];   // 16.2 KB: staged x patch, 8 channels
    __shared__ float s_Y[KK][PT][PSTR];   // 18.2 KB: channel-collapsed planes Y_k

    const int tid = threadIdx.x;
    const int tx = tid & 15;
    const int ty = tid >> 4;
    const int x0 = blockIdx.x * TS;
    const int y0 = blockIdx.y * TS;
    const int b  = blockIdx.z;
    const int ho = y0 + ty;
    const int wo = x0 + tx;
    const bool valid = (ho < HO) && (wo < WO);

    const float* xb = x + (size_t)b * CC * HH * WW;

    // Y-cell ownership: 22*22 = 484 cells, thread t owns cell t (+ t+256 if < 484)
    const int cell0 = tid;
    const int cell1 = tid + 256;
    const int r0c = cell0 / PT, c0c = cell0 - r0c * PT;
    const int r1c = cell1 / PT, c1c = cell1 - r1c * PT;
    const bool has1 = (cell1 < PT * PT);

    float accO[NOFF];
    #pragma unroll
    for (int o = 0; o < NOFF; ++o) accO[o] = offset_b[o];   // uniform -> s_load
    float accY0[KK] = {};
    float accY1[KK] = {};

    for (int cg = 0; cg < CC; cg += CH) {
        __syncthreads();   // protect previous stage's s_x reads
        // stage 8 channel patches (22x22, zero-padded outside image)
        for (int i = tid; i < CH * PT * PT; i += 256) {
            int cc  = i / (PT * PT);
            int rem = i - cc * (PT * PT);
            int r   = rem / PT;
            int col = rem - r * PT;
            int gy = y0 - S + r;
            int gx = x0 - S + col;
            float v = 0.0f;
            if (gy >= 0 && gy < HH && gx >= 0 && gx < WW)
                v = xb[(size_t)(cg + cc) * (HH * WW) + gy * WW + gx];
            s_x[cc][r][col] = v;
        }
        __syncthreads();

        #pragma unroll
        for (int cc = 0; cc < CH; ++cc) {
            // ---- offset conv accumulation (weights: wave-uniform scalar loads) ----
            float xv[KK];
            #pragma unroll
            for (int kh = 0; kh < 3; ++kh)
                #pragma unroll
                for (int kw = 0; kw < 3; ++kw)
                    xv[kh * 3 + kw] = s_x[cc][ty + kh + S][tx + kw + S];
            const float* wc = offset_w + (size_t)(cg + cc) * KK;
            #pragma unroll
            for (int o = 0; o < NOFF; ++o) {
                #pragma unroll
                for (int t = 0; t < KK; ++t)
                    accO[o] = fmaf(xv[t], wc[o * (CC * KK) + t], accO[o]);
            }
            // ---- Y = sum_c dw[c,k] * x[c]  (1x1 conv, per owned cell) ----
            const float* dwc = deform_w + (size_t)(cg + cc) * KK;
            float v0 = s_x[cc][r0c][c0c];
            #pragma unroll
            for (int k = 0; k < KK; ++k) accY0[k] = fmaf(v0, dwc[k], accY0[k]);
            if (has1) {
                float v1 = s_x[cc][r1c][c1c];
                #pragma unroll
                for (int k = 0; k < KK; ++k) accY1[k] = fmaf(v1, dwc[k], accY1[k]);
            }
        }
    }

    // publish Y planes (s_Y disjoint from s_x, so no barrier needed before writes)
    #pragma unroll
    for (int k = 0; k < KK; ++k) s_Y[k][r0c][c0c] = accY0[k];
    if (has1) {
        #pragma unroll
        for (int k = 0; k < KK; ++k) s_Y[k][r1c][c1c] = accY1[k];
    }
    __syncthreads();   // last barrier; early-outs below are safe

    if (!valid) return;

    // ---- deformable bilinear gather on the 9 collapsed planes ----
    float acc = deform_b[0];

    #pragma unroll
    for (int k = 0; k < KK; ++k) {
        const int kh = k / 3, kw = k % 3;
        float py = (float)(ho + kh) + accO[2 * k];
        float px = (float)(wo + kw) + accO[2 * k + 1];
        float y0f = floorf(py), x0f = floorf(px);
        float ly = py - y0f, lx = px - x0f;
        int yi0 = (int)y0f, xi0 = (int)x0f;
        int ry = yi0 - (y0 - S);
        int rx = xi0 - (x0 - S);
        float w00 = (1.0f - ly) * (1.0f - lx);
        float w01 = (1.0f - ly) * lx;
        float w10 = ly * (1.0f - lx);
        float w11 = ly * lx;
        float g;
        if ((unsigned)ry <= (unsigned)(PT - 2) && (unsigned)rx <= (unsigned)(PT - 2)) {
            // fast path: all 4 corners inside the staged patch. Out-of-image
            // cells were staged as 0 == reference's valid-mask contribution.
            const float* tp = &s_Y[k][0][0];
            int id = ry * PSTR + rx;
            g = w00 * tp[id]        + w01 * tp[id + 1]
              + w10 * tp[id + PSTR] + w11 * tp[id + PSTR + 1];
        } else {
            // rare fallback: exact global gather over all channels
            int yi1 = yi0 + 1, xi1 = xi0 + 1;
            float m00 = (yi0 >= 0 && yi0 < HH && xi0 >= 0 && xi0 < WW) ? w00 : 0.0f;
            float m01 = (yi0 >= 0 && yi0 < HH && xi1 >= 0 && xi1 < WW) ? w01 : 0.0f;
            float m10 = (yi1 >= 0 && yi1 < HH && xi0 >= 0 && xi0 < WW) ? w10 : 0.0f;
            float m11 = (yi1 >= 0 && yi1 < HH && xi1 >= 0 && xi1 < WW) ? w11 : 0.0f;
            int y0cl = min(max(yi0, 0), HH - 1), y1cl = min(max(yi1, 0), HH - 1);
            int x0cl = min(max(xi0, 0), WW - 1), x1cl = min(max(xi1, 0), WW - 1);
            g = 0.0f;
            for (int c = 0; c < CC; ++c) {
                const float* xc = xb + (size_t)c * (HH * WW);
                float gc = m00 * xc[y0cl * WW + x0cl] + m01 * xc[y0cl * WW + x1cl]
                         + m10 * xc[y1cl * WW + x0cl] + m11 * xc[y1cl * WW + x1cl];
                g = fmaf(gc, deform_w[(size_t)c * KK + k], g);
            }
        }
        acc += g;
    }

    out[(size_t)b * (HO * WO) + ho * WO + wo] = acc;
}

extern "C" void kernel_launch(void* const* d_in, const int* in_sizes, int n_in,
                              void* d_out, int out_size, void* d_ws, size_t ws_size,
                              hipStream_t stream) {
    const float* x        = (const float*)d_in[0];
    const float* offset_w = (const float*)d_in[1];
    const float* offset_b = (const float*)d_in[2];
    const float* deform_w = (const float*)d_in[3];
    const float* deform_b = (const float*)d_in[4];
    float* out = (float*)d_out;

    dim3 block(256);
    dim3 grid((WO + TS - 1) / TS, (HO + TS - 1) / TS, BB);  // 16 x 16 x 4
    hipLaunchKernelGGL(deform_fused_kernel, grid, block, 0, stream,
                       x, offset_w, offset_b, deform_w, deform_b, out);
}

// Round 4
// 172.296 us; speedup vs baseline: 3.2322x; 2.9486x over previous
//
#include <hip/hip_runtime.h>
#include <hip/hip_bf16.h>

#define BB 4
#define CC 64
#define HH 256
#define WW 256
#define KK 9
#define NOFF 18
#define HO 254
#define WO 254
#define TS 16          // output tile side (16x16 pixels per block)
#define S  2           // gather slack
#define PT 22          // staged patch side: TS + 2 + 2*S
#define NCELL (PT*PT)  // 484

// ---- LDS layout (one aliased arena) ----
// phase A (staging + MFMA):
//   s_x   @ 0       : 484 cells * 32 ch * 2B (bf16, XOR-swizzled)   = 30976
//   s_Bc  @ 30976   : conv weights [9 tap][20 o][72 c] bf16          = 25920
//   s_dw  @ 56896   : deform weights [16 tap][72 c] bf16             =  2304
// phase B (aliases s_x/s_Bc, both dead):
//   s_off @ 0       : [18][257] f32                                  = 18504
//   s_Y   @ 18504   : [9][485] f32                                   = 17460
#define OFF_SX   0
#define OFF_BC   30976
#define OFF_DW   56896
#define SMEM_SZ  59200
#define OFF_SOFF 0
#define OFF_SY   18504

#define SWZ(lin) ((lin) ^ ((((lin) >> 7) & 7) << 4))

typedef __attribute__((ext_vector_type(8))) short bf16x8;
typedef __attribute__((ext_vector_type(4))) float f32x4;

static __device__ __forceinline__ unsigned short f2bf(float v) {
    __hip_bfloat16 h = __float2bfloat16(v);
    union { __hip_bfloat16 b; unsigned short u; } cv; cv.b = h; return cv.u;
}

__global__ __launch_bounds__(256) void deform_fused_kernel(
    const float* __restrict__ x,
    const float* __restrict__ offset_w,
    const float* __restrict__ offset_b,
    const float* __restrict__ deform_w,
    const float* __restrict__ deform_b,
    float* __restrict__ out)
{
    __shared__ __align__(16) unsigned char smem[SMEM_SZ];

    const int tid = threadIdx.x;
    const int x0 = blockIdx.x * TS;
    const int y0 = blockIdx.y * TS;
    const int b  = blockIdx.z;
    const float* xb = x + (size_t)b * CC * HH * WW;

    // ---------------- stage weights (bf16 repack) ----------------
    // conv weights: offset_w[o][c][tap] -> s_Bc[tap][o][c] (o padded to 20, zeros)
    for (int i = tid; i < 9 * 20 * 64; i += 256) {
        int tap = i / 1280;
        int rem = i - tap * 1280;
        int o   = rem >> 6;
        int c   = rem & 63;
        float v = (o < NOFF) ? offset_w[((size_t)o * CC + c) * KK + tap] : 0.0f;
        *(unsigned short*)(smem + OFF_BC + ((size_t)(tap * 20 + o) * 144 + c * 2)) = f2bf(v);
    }
    // deform weights: deform_w[c][tap] -> s_dw[tap][c] (tap padded to 16, zeros)
    for (int i = tid; i < 16 * 64; i += 256) {
        int tap = i >> 6;
        int c   = i & 63;
        float v = (tap < KK) ? deform_w[(size_t)c * KK + tap] : 0.0f;
        *(unsigned short*)(smem + OFF_DW + (size_t)tap * 144 + c * 2) = f2bf(v);
    }

    // ---------------- stage x chunk (32 channels, bf16, swizzled) ----------------
    auto stage_x = [&](int cc0) {
        for (int i = tid; i < 16 * 512; i += 256) {
            int cpair = i >> 9;          // 0..15 -> channels cc0+2*cpair, +1
            int cell  = i & 511;
            if (cell >= NCELL) continue;
            int r   = cell / PT;
            int col = cell - r * PT;
            int gy = y0 - S + r;
            int gx = x0 - S + col;
            float v0 = 0.0f, v1 = 0.0f;
            if (gy >= 0 && gy < HH && gx >= 0 && gx < WW) {
                const float* p = xb + (size_t)(cc0 + 2 * cpair) * (HH * WW) + gy * WW + gx;
                v0 = p[0];
                v1 = p[HH * WW];
            }
            __hip_bfloat162 h2 = __float22bfloat162_rn(make_float2(v0, v1));
            unsigned int u; __builtin_memcpy(&u, &h2, 4);
            int lin = cell * 64 + cpair * 4;
            *(unsigned int*)(smem + OFF_SX + SWZ(lin)) = u;
        }
    };

    stage_x(0);
    __syncthreads();

    // ---------------- MFMA phase ----------------
    const int w  = tid >> 6;
    const int l  = tid & 63;
    const int lr = l & 15;   // A-row / B-col / D-col lane component
    const int lk = l >> 4;   // k-group (8 bf16 each)

    float bias0 = offset_b[lr];                              // o = lr (0..15)
    float bias1 = (lr < 2) ? offset_b[16 + lr] : 0.0f;       // o = 16+lr
    f32x4 accC[4][2];
    #pragma unroll
    for (int mi = 0; mi < 4; ++mi) {
        #pragma unroll
        for (int reg = 0; reg < 4; ++reg) { accC[mi][0][reg] = bias0; accC[mi][1][reg] = bias1; }
    }
    f32x4 accY[8];
    #pragma unroll
    for (int yi = 0; yi < 8; ++yi) accY[yi] = (f32x4){0.f, 0.f, 0.f, 0.f};

    #pragma unroll
    for (int half = 0; half < 2; ++half) {
        const int cc0 = half * 32;
        const int koff = lk * 16;          // byte offset of this lane's 8 channels (chunk-rel)

        // ---- offset conv: 9 tap-GEMMs, K=32 per half ----
        #pragma unroll
        for (int tap = 0; tap < 9; ++tap) {
            const int kh = tap / 3, kw = tap % 3;
            bf16x8 b0 = *(const bf16x8*)(smem + OFF_BC + (size_t)(tap * 20 + lr) * 144 + (cc0 + lk * 8) * 2);
            int o1 = 16 + lr; if (o1 > 19) o1 = 19;
            bf16x8 b1 = *(const bf16x8*)(smem + OFF_BC + (size_t)(tap * 20 + o1) * 144 + (cc0 + lk * 8) * 2);
            #pragma unroll
            for (int mi = 0; mi < 4; ++mi) {
                int row  = 4 * w + mi;                       // image row i within tile
                int cell = (row + kh + S) * PT + (lr + kw + S);
                int lin  = cell * 64 + koff;
                bf16x8 a = *(const bf16x8*)(smem + OFF_SX + SWZ(lin));
                accC[mi][0] = __builtin_amdgcn_mfma_f32_16x16x32_bf16(a, b0, accC[mi][0], 0, 0, 0);
                accC[mi][1] = __builtin_amdgcn_mfma_f32_16x16x32_bf16(a, b1, accC[mi][1], 0, 0, 0);
            }
        }

        // ---- Y collapse: M=484 cells, N=9(pad16), K=32 per half ----
        bf16x8 bY = *(const bf16x8*)(smem + OFF_DW + (size_t)lr * 144 + (cc0 + lk * 8) * 2);
        #pragma unroll
        for (int yi = 0; yi < 8; ++yi) {
            int tile = 8 * w + yi;
            if (tile < 31) {
                int cell = tile * 16 + lr; if (cell > NCELL - 1) cell = NCELL - 1;
                int lin  = cell * 64 + koff;
                bf16x8 a = *(const bf16x8*)(smem + OFF_SX + SWZ(lin));
                accY[yi] = __builtin_amdgcn_mfma_f32_16x16x32_bf16(a, bY, accY[yi], 0, 0, 0);
            }
        }

        if (half == 0) {
            __syncthreads();   // chunk-0 reads done
            stage_x(32);
            __syncthreads();   // chunk-1 staged
        }
    }

    __syncthreads();   // all MFMA reads done; arena can be re-used

    // ---- redistribute: conv D -> s_off[o][pixel], Y D -> s_Y[tap][cell] ----
    float* s_off = (float*)(smem + OFF_SOFF);
    float* s_Y   = (float*)(smem + OFF_SY);
    #pragma unroll
    for (int mi = 0; mi < 4; ++mi) {
        #pragma unroll
        for (int nt = 0; nt < 2; ++nt) {
            int o = nt * 16 + lr;
            if (o < NOFF) {
                int pbase = (4 * w + mi) * 16 + lk * 4;      // pixel = i*16 + j
                #pragma unroll
                for (int reg = 0; reg < 4; ++reg)
                    s_off[o * 257 + pbase + reg] = accC[mi][nt][reg];
            }
        }
    }
    #pragma unroll
    for (int yi = 0; yi < 8; ++yi) {
        int tile = 8 * w + yi;
        if (tile < 31 && lr < KK) {
            #pragma unroll
            for (int reg = 0; reg < 4; ++reg) {
                int cell = tile * 16 + lk * 4 + reg;
                if (cell < NCELL) s_Y[lr * 485 + cell] = accY[yi][reg];
            }
        }
    }
    __syncthreads();   // last barrier; early-outs below are safe

    // ---------------- gather phase (per-pixel) ----------------
    const int ty = tid >> 4, tx = tid & 15;
    const int ho = y0 + ty, wo = x0 + tx;
    if (ho >= HO || wo >= WO) return;

    float acc = deform_b[0];

    #pragma unroll
    for (int k = 0; k < KK; ++k) {
        const int kh = k / 3, kw = k % 3;
        float dy = s_off[(2 * k) * 257 + tid];
        float dx = s_off[(2 * k + 1) * 257 + tid];
        float py = (float)(ho + kh) + dy;
        float px = (float)(wo + kw) + dx;
        float y0f = floorf(py), x0f = floorf(px);
        float ly = py - y0f, lx = px - x0f;
        int yi0 = (int)y0f, xi0 = (int)x0f;
        int ry = yi0 - (y0 - S);
        int rx = xi0 - (x0 - S);
        float w00 = (1.0f - ly) * (1.0f - lx);
        float w01 = (1.0f - ly) * lx;
        float w10 = ly * (1.0f - lx);
        float w11 = ly * lx;
        float g;
        if ((unsigned)ry <= (unsigned)(PT - 2) && (unsigned)rx <= (unsigned)(PT - 2)) {
            // fast path: 4 corners inside staged patch; out-of-image cells staged 0
            const float* tp = s_Y + k * 485;
            int id = ry * PT + rx;
            g = w00 * tp[id]      + w01 * tp[id + 1]
              + w10 * tp[id + PT] + w11 * tp[id + PT + 1];
        } else {
            // rare fallback: exact global gather over channels (f32)
            int yi1 = yi0 + 1, xi1 = xi0 + 1;
            float m00 = (yi0 >= 0 && yi0 < HH && xi0 >= 0 && xi0 < WW) ? w00 : 0.0f;
            float m01 = (yi0 >= 0 && yi0 < HH && xi1 >= 0 && xi1 < WW) ? w01 : 0.0f;
            float m10 = (yi1 >= 0 && yi1 < HH && xi0 >= 0 && xi0 < WW) ? w10 : 0.0f;
            float m11 = (yi1 >= 0 && yi1 < HH && xi1 >= 0 && xi1 < WW) ? w11 : 0.0f;
            int y0cl = min(max(yi0, 0), HH - 1), y1cl = min(max(yi1, 0), HH - 1);
            int x0cl = min(max(xi0, 0), WW - 1), x1cl = min(max(xi1, 0), WW - 1);
            g = 0.0f;
            for (int c = 0; c < CC; ++c) {
                const float* xc = xb + (size_t)c * (HH * WW);
                float gc = m00 * xc[y0cl * WW + x0cl] + m01 * xc[y0cl * WW + x1cl]
                         + m10 * xc[y1cl * WW + x0cl] + m11 * xc[y1cl * WW + x1cl];
                gc *= deform_w[(size_t)c * KK + k];
                g += gc;
            }
        }
        acc += g;
    }

    out[(size_t)b * (HO * WO) + ho * WO + wo] = acc;
}

extern "C" void kernel_launch(void* const* d_in, const int* in_sizes, int n_in,
                              void* d_out, int out_size, void* d_ws, size_t ws_size,
                              hipStream_t stream) {
    const float* x        = (const float*)d_in[0];
    const float* offset_w = (const float*)d_in[1];
    const float* offset_b = (const float*)d_in[2];
    const float* deform_w = (const float*)d_in[3];
    const float* deform_b = (const float*)d_in[4];
    float* out = (float*)d_out;

    dim3 block(256);
    dim3 grid((WO + TS - 1) / TS, (HO + TS - 1) / TS, BB);  // 16 x 16 x 4
    hipLaunchKernelGGL(deform_fused_kernel, grid, block, 0, stream,
                       x, offset_w, offset_b, deform_w, deform_b, out);
}

// Round 5
// 79.636 us; speedup vs baseline: 6.9930x; 2.1635x over previous
//
#include <hip/hip_runtime.h>
#include <hip/hip_bf16.h>

#define BB 4
#define CC 64
#define HH 256
#define WW 256
#define KK 9
#define NOFF 18
#define HO 254
#define WO 254
#define NPIX (HO*WO)           // 64516
#define TS 16

// ---------------- workspace layout ----------------
// WS_BC : bf16 conv weights [9 tap][20 o][row stride 144B]          = 25920 B
// WS_DW : bf16 deform weights [16 tap][row stride 144B]             =  2304 B
// WS_OFF: f32 off[B][18][NPIX]                                      = 18,580,608 B
// WS_Y  : f32 Y[B][9][HH*WW]                                        =  9,437,184 B
#define WS_BC   0
#define WS_DW   25920
#define WS_OFF  32768
#define WS_Y    (WS_OFF + BB*NOFF*NPIX*4)           // 32768 + 18580608
#define WS_NEED (WS_Y + BB*KK*HH*WW*4)              // 28,050,560

#define SWZ(lin) ((lin) ^ ((((lin) >> 7) & 7) << 4))

typedef __attribute__((ext_vector_type(8))) short bf16x8;
typedef __attribute__((ext_vector_type(4))) float f32x4;

static __device__ __forceinline__ unsigned short f2bf(float v) {
    __hip_bfloat16 h = __float2bfloat16(v);
    union { __hip_bfloat16 b; unsigned short u; } cv; cv.b = h; return cv.u;
}

// ================= kernel W: one-time weight repack =================
__global__ __launch_bounds__(256) void repack_kernel(
    const float* __restrict__ offset_w,
    const float* __restrict__ deform_w,
    unsigned char* __restrict__ ws)
{
    int tid = threadIdx.x;
    for (int i = tid; i < 9 * 20 * 64; i += 256) {
        int tap = i / 1280;
        int rem = i - tap * 1280;
        int o   = rem >> 6;
        int c   = rem & 63;
        float v = (o < NOFF) ? offset_w[((size_t)o * CC + c) * KK + tap] : 0.0f;
        *(unsigned short*)(ws + WS_BC + (size_t)(tap * 20 + o) * 144 + c * 2) = f2bf(v);
    }
    for (int i = tid; i < 16 * 64; i += 256) {
        int tap = i >> 6;
        int c   = i & 63;
        float v = (tap < KK) ? deform_w[(size_t)c * KK + tap] : 0.0f;
        *(unsigned short*)(ws + WS_DW + (size_t)tap * 144 + c * 2) = f2bf(v);
    }
}

// ================= kernel C: offset conv + Y collapse (MFMA) =================
#define PTC 18                 // patch side: TS + 2
#define NCELLC (PTC*PTC)       // 324
#define OFF_SX 0               // 324*64 = 20736 (bf16 x patch, 32ch/chunk, swizzled)
#define OFF_BC 20736           // 25920
#define OFF_DW 46656           // 2304
#define SMEM_C 48960

__global__ __launch_bounds__(256) void convY_kernel(
    const float* __restrict__ x,
    const float* __restrict__ offset_b,
    const unsigned char* __restrict__ ws_w,
    float* __restrict__ off,      // [B][18][NPIX]
    float* __restrict__ Y)        // [B][9][HH*WW]
{
    __shared__ __align__(16) unsigned char smem[SMEM_C];

    const int tid = threadIdx.x;
    const int x0 = blockIdx.x * TS;
    const int y0 = blockIdx.y * TS;
    const int b  = blockIdx.z;
    const float* xb = x + (size_t)b * CC * HH * WW;

    // stage repacked weights (contiguous 28224 B = 1764 x 16B)
    {
        const uint4* src = (const uint4*)ws_w;
        uint4* dst = (uint4*)(smem + OFF_BC);
        for (int i = tid; i < 1764; i += 256) dst[i] = src[i];
    }

    auto stage_x = [&](int cc0) {
        for (int i = tid; i < 16 * NCELLC; i += 256) {
            int cpair = i / NCELLC;
            int cell  = i - cpair * NCELLC;
            int r   = cell / PTC;
            int col = cell - r * PTC;
            int gy = y0 + r;
            int gx = x0 + col;
            float v0 = 0.0f, v1 = 0.0f;
            if (gy < HH && gx < WW) {
                const float* p = xb + (size_t)(cc0 + 2 * cpair) * (HH * WW) + gy * WW + gx;
                v0 = p[0];
                v1 = p[HH * WW];
            }
            __hip_bfloat162 h2 = __float22bfloat162_rn(make_float2(v0, v1));
            unsigned int u; __builtin_memcpy(&u, &h2, 4);
            int lin = cell * 64 + cpair * 4;
            *(unsigned int*)(smem + OFF_SX + SWZ(lin)) = u;
        }
    };

    stage_x(0);
    __syncthreads();

    const int w  = tid >> 6;
    const int l  = tid & 63;
    const int lr = l & 15;
    const int lk = l >> 4;

    float bias0 = offset_b[lr];
    float bias1 = (lr < 2) ? offset_b[16 + lr] : 0.0f;
    f32x4 accC[4][2];
    #pragma unroll
    for (int mi = 0; mi < 4; ++mi)
        #pragma unroll
        for (int reg = 0; reg < 4; ++reg) { accC[mi][0][reg] = bias0; accC[mi][1][reg] = bias1; }
    f32x4 accY[4];
    #pragma unroll
    for (int mi = 0; mi < 4; ++mi) accY[mi] = (f32x4){0.f, 0.f, 0.f, 0.f};

    #pragma unroll
    for (int half = 0; half < 2; ++half) {
        const int cc0 = half * 32;
        const int o1 = (16 + lr > 19) ? 19 : 16 + lr;
        bf16x8 bY = *(const bf16x8*)(smem + OFF_DW + (size_t)lr * 144 + (cc0 + lk * 8) * 2);

        #pragma unroll
        for (int tap = 0; tap < 9; ++tap) {
            const int kh = tap / 3, kw = tap % 3;
            bf16x8 b0 = *(const bf16x8*)(smem + OFF_BC + (size_t)(tap * 20 + lr) * 144 + (cc0 + lk * 8) * 2);
            bf16x8 b1 = *(const bf16x8*)(smem + OFF_BC + (size_t)(tap * 20 + o1) * 144 + (cc0 + lk * 8) * 2);
            #pragma unroll
            for (int mi = 0; mi < 4; ++mi) {
                int cell = (4 * w + mi + kh) * PTC + (lr + kw);
                bf16x8 a = *(const bf16x8*)(smem + OFF_SX + SWZ(cell * 64 + lk * 16));
                accC[mi][0] = __builtin_amdgcn_mfma_f32_16x16x32_bf16(a, b0, accC[mi][0], 0, 0, 0);
                accC[mi][1] = __builtin_amdgcn_mfma_f32_16x16x32_bf16(a, b1, accC[mi][1], 0, 0, 0);
                if (tap == 0)
                    accY[mi] = __builtin_amdgcn_mfma_f32_16x16x32_bf16(a, bY, accY[mi], 0, 0, 0);
            }
        }

        if (half == 0) {
            __syncthreads();
            stage_x(32);
            __syncthreads();
        }
    }

    // ---- store offsets: D col(lr)=o, row(lk*4+reg)=image column ----
    #pragma unroll
    for (int mi = 0; mi < 4; ++mi) {
        int ho = y0 + 4 * w + mi;
        #pragma unroll
        for (int nt = 0; nt < 2; ++nt) {
            int o = nt * 16 + lr;
            if (o < NOFF && ho < HO) {
                float* dst = off + ((size_t)b * NOFF + o) * NPIX + (size_t)ho * WO;
                #pragma unroll
                for (int reg = 0; reg < 4; ++reg) {
                    int wo = x0 + lk * 4 + reg;
                    if (wo < WO) dst[wo] = accC[mi][nt][reg];
                }
            }
        }
        // ---- store Y: col(lr)=tap, row=image column; rows y0+4w+mi < 256 always ----
        if (lr < KK) {
            float* dst = Y + ((size_t)b * KK + lr) * (HH * WW) + (size_t)(y0 + 4 * w + mi) * WW + x0;
            #pragma unroll
            for (int reg = 0; reg < 4; ++reg)
                dst[lk * 4 + reg] = accY[mi][reg];
        }
    }
}

// ================= kernel G: bilinear gather on collapsed planes =================
__global__ __launch_bounds__(256) void gather_kernel(
    const float* __restrict__ off,     // [B][18][NPIX]
    const float* __restrict__ Y,       // [B][9][HH*WW]
    const float* __restrict__ deform_b,
    float* __restrict__ out)
{
    int p2 = blockIdx.x * 256 + threadIdx.x;
    if (p2 >= NPIX) return;
    int b = blockIdx.y;
    int ho = p2 / WO;
    int wo = p2 - ho * WO;

    const float* offb = off + (size_t)b * NOFF * NPIX;
    const float* Yb   = Y + (size_t)b * KK * (HH * WW);

    float acc = deform_b[0];

    #pragma unroll
    for (int k = 0; k < KK; ++k) {
        const int kh = k / 3, kw = k % 3;
        float dy = offb[(size_t)(2 * k) * NPIX + p2];
        float dx = offb[(size_t)(2 * k + 1) * NPIX + p2];
        float py = (float)(ho + kh) + dy;
        float px = (float)(wo + kw) + dx;
        float y0f = floorf(py), x0f = floorf(px);
        float ly = py - y0f, lx = px - x0f;
        int yi0 = (int)y0f, xi0 = (int)x0f;
        int yi1 = yi0 + 1, xi1 = xi0 + 1;

        float w00 = (1.0f - ly) * (1.0f - lx);
        float w01 = (1.0f - ly) * lx;
        float w10 = ly * (1.0f - lx);
        float w11 = ly * lx;
        if (!(yi0 >= 0 && yi0 < HH && xi0 >= 0 && xi0 < WW)) w00 = 0.0f;
        if (!(yi0 >= 0 && yi0 < HH && xi1 >= 0 && xi1 < WW)) w01 = 0.0f;
        if (!(yi1 >= 0 && yi1 < HH && xi0 >= 0 && xi0 < WW)) w10 = 0.0f;
        if (!(yi1 >= 0 && yi1 < HH && xi1 >= 0 && xi1 < WW)) w11 = 0.0f;

        int y0c = min(max(yi0, 0), HH - 1);
        int y1c = min(max(yi1, 0), HH - 1);
        int x0c = min(max(xi0, 0), WW - 1);
        int x1c = min(max(xi1, 0), WW - 1);

        const float* Yk = Yb + (size_t)k * (HH * WW);
        acc += w00 * Yk[y0c * WW + x0c] + w01 * Yk[y0c * WW + x1c]
             + w10 * Yk[y1c * WW + x0c] + w11 * Yk[y1c * WW + x1c];
    }

    out[(size_t)b * NPIX + p2] = acc;
}

// ================= fallback: R4 fused kernel (used if ws too small) =================
#define S  2
#define PT 22
#define NCELL (PT*PT)
#define FOFF_SX   0
#define FOFF_BC   30976
#define FOFF_DW   56896
#define FSMEM_SZ  59200
#define FOFF_SOFF 0
#define FOFF_SY   18504

__global__ __launch_bounds__(256) void deform_fused_fallback(
    const float* __restrict__ x,
    const float* __restrict__ offset_w,
    const float* __restrict__ offset_b,
    const float* __restrict__ deform_w,
    const float* __restrict__ deform_b,
    float* __restrict__ out)
{
    __shared__ __align__(16) unsigned char smem[FSMEM_SZ];

    const int tid = threadIdx.x;
    const int x0 = blockIdx.x * TS;
    const int y0 = blockIdx.y * TS;
    const int b  = blockIdx.z;
    const float* xb = x + (size_t)b * CC * HH * WW;

    for (int i = tid; i < 9 * 20 * 64; i += 256) {
        int tap = i / 1280;
        int rem = i - tap * 1280;
        int o   = rem >> 6;
        int c   = rem & 63;
        float v = (o < NOFF) ? offset_w[((size_t)o * CC + c) * KK + tap] : 0.0f;
        *(unsigned short*)(smem + FOFF_BC + ((size_t)(tap * 20 + o) * 144 + c * 2)) = f2bf(v);
    }
    for (int i = tid; i < 16 * 64; i += 256) {
        int tap = i >> 6;
        int c   = i & 63;
        float v = (tap < KK) ? deform_w[(size_t)c * KK + tap] : 0.0f;
        *(unsigned short*)(smem + FOFF_DW + (size_t)tap * 144 + c * 2) = f2bf(v);
    }

    auto stage_x = [&](int cc0) {
        for (int i = tid; i < 16 * 512; i += 256) {
            int cpair = i >> 9;
            int cell  = i & 511;
            if (cell >= NCELL) continue;
            int r   = cell / PT;
            int col = cell - r * PT;
            int gy = y0 - S + r;
            int gx = x0 - S + col;
            float v0 = 0.0f, v1 = 0.0f;
            if (gy >= 0 && gy < HH && gx >= 0 && gx < WW) {
                const float* p = xb + (size_t)(cc0 + 2 * cpair) * (HH * WW) + gy * WW + gx;
                v0 = p[0];
                v1 = p[HH * WW];
            }
            __hip_bfloat162 h2 = __float22bfloat162_rn(make_float2(v0, v1));
            unsigned int u; __builtin_memcpy(&u, &h2, 4);
            int lin = cell * 64 + cpair * 4;
            *(unsigned int*)(smem + FOFF_SX + SWZ(lin)) = u;
        }
    };

    stage_x(0);
    __syncthreads();

    const int w  = tid >> 6;
    const int l  = tid & 63;
    const int lr = l & 15;
    const int lk = l >> 4;

    float bias0 = offset_b[lr];
    float bias1 = (lr < 2) ? offset_b[16 + lr] : 0.0f;
    f32x4 accC[4][2];
    #pragma unroll
    for (int mi = 0; mi < 4; ++mi)
        #pragma unroll
        for (int reg = 0; reg < 4; ++reg) { accC[mi][0][reg] = bias0; accC[mi][1][reg] = bias1; }
    f32x4 accY[8];
    #pragma unroll
    for (int yi = 0; yi < 8; ++yi) accY[yi] = (f32x4){0.f, 0.f, 0.f, 0.f};

    #pragma unroll
    for (int half = 0; half < 2; ++half) {
        const int cc0 = half * 32;
        const int koff = lk * 16;

        #pragma unroll
        for (int tap = 0; tap < 9; ++tap) {
            const int kh = tap / 3, kw = tap % 3;
            bf16x8 b0 = *(const bf16x8*)(smem + FOFF_BC + (size_t)(tap * 20 + lr) * 144 + (cc0 + lk * 8) * 2);
            int o1 = 16 + lr; if (o1 > 19) o1 = 19;
            bf16x8 b1 = *(const bf16x8*)(smem + FOFF_BC + (size_t)(tap * 20 + o1) * 144 + (cc0 + lk * 8) * 2);
            #pragma unroll
            for (int mi = 0; mi < 4; ++mi) {
                int row  = 4 * w + mi;
                int cell = (row + kh + S) * PT + (lr + kw + S);
                bf16x8 a = *(const bf16x8*)(smem + FOFF_SX + SWZ(cell * 64 + koff));
                accC[mi][0] = __builtin_amdgcn_mfma_f32_16x16x32_bf16(a, b0, accC[mi][0], 0, 0, 0);
                accC[mi][1] = __builtin_amdgcn_mfma_f32_16x16x32_bf16(a, b1, accC[mi][1], 0, 0, 0);
            }
        }

        bf16x8 bY = *(const bf16x8*)(smem + FOFF_DW + (size_t)lr * 144 + (cc0 + lk * 8) * 2);
        #pragma unroll
        for (int yi = 0; yi < 8; ++yi) {
            int tile = 8 * w + yi;
            if (tile < 31) {
                int cell = tile * 16 + lr; if (cell > NCELL - 1) cell = NCELL - 1;
                bf16x8 a = *(const bf16x8*)(smem + FOFF_SX + SWZ(cell * 64 + koff));
                accY[yi] = __builtin_amdgcn_mfma_f32_16x16x32_bf16(a, bY, accY[yi], 0, 0, 0);
            }
        }

        if (half == 0) {
            __syncthreads();
            stage_x(32);
            __syncthreads();
        }
    }

    __syncthreads();

    float* s_off = (float*)(smem + FOFF_SOFF);
    float* s_Y   = (float*)(smem + FOFF_SY);
    #pragma unroll
    for (int mi = 0; mi < 4; ++mi) {
        #pragma unroll
        for (int nt = 0; nt < 2; ++nt) {
            int o = nt * 16 + lr;
            if (o < NOFF) {
                int pbase = (4 * w + mi) * 16 + lk * 4;
                #pragma unroll
                for (int reg = 0; reg < 4; ++reg)
                    s_off[o * 257 + pbase + reg] = accC[mi][nt][reg];
            }
        }
    }
    #pragma unroll
    for (int yi = 0; yi < 8; ++yi) {
        int tile = 8 * w + yi;
        if (tile < 31 && lr < KK) {
            #pragma unroll
            for (int reg = 0; reg < 4; ++reg) {
                int cell = tile * 16 + lk * 4 + reg;
                if (cell < NCELL) s_Y[lr * 485 + cell] = accY[yi][reg];
            }
        }
    }
    __syncthreads();

    const int ty = tid >> 4, tx = tid & 15;
    const int ho = y0 + ty, wo = x0 + tx;
    if (ho >= HO || wo >= WO) return;

    float acc = deform_b[0];

    #pragma unroll
    for (int k = 0; k < KK; ++k) {
        const int kh = k / 3, kw = k % 3;
        float dy = s_off[(2 * k) * 257 + tid];
        float dx = s_off[(2 * k + 1) * 257 + tid];
        float py = (float)(ho + kh) + dy;
        float px = (float)(wo + kw) + dx;
        float y0f = floorf(py), x0f = floorf(px);
        float ly = py - y0f, lx = px - x0f;
        int yi0 = (int)y0f, xi0 = (int)x0f;
        int ry = yi0 - (y0 - S);
        int rx = xi0 - (x0 - S);
        float w00 = (1.0f - ly) * (1.0f - lx);
        float w01 = (1.0f - ly) * lx;
        float w10 = ly * (1.0f - lx);
        float w11 = ly * lx;
        float g;
        if ((unsigned)ry <= (unsigned)(PT - 2) && (unsigned)rx <= (unsigned)(PT - 2)) {
            const float* tp = s_Y + k * 485;
            int id = ry * PT + rx;
            g = w00 * tp[id]      + w01 * tp[id + 1]
              + w10 * tp[id + PT] + w11 * tp[id + PT + 1];
        } else {
            int yi1 = yi0 + 1, xi1 = xi0 + 1;
            float m00 = (yi0 >= 0 && yi0 < HH && xi0 >= 0 && xi0 < WW) ? w00 : 0.0f;
            float m01 = (yi0 >= 0 && yi0 < HH && xi1 >= 0 && xi1 < WW) ? w01 : 0.0f;
            float m10 = (yi1 >= 0 && yi1 < HH && xi0 >= 0 && xi0 < WW) ? w10 : 0.0f;
            float m11 = (yi1 >= 0 && yi1 < HH && xi1 >= 0 && xi1 < WW) ? w11 : 0.0f;
            int y0cl = min(max(yi0, 0), HH - 1), y1cl = min(max(yi1, 0), HH - 1);
            int x0cl = min(max(xi0, 0), WW - 1), x1cl = min(max(xi1, 0), WW - 1);
            g = 0.0f;
            for (int c = 0; c < CC; ++c) {
                const float* xc = xb + (size_t)c * (HH * WW);
                float gc = m00 * xc[y0cl * WW + x0cl] + m01 * xc[y0cl * WW + x1cl]
                         + m10 * xc[y1cl * WW + x0cl] + m11 * xc[y1cl * WW + x1cl];
                gc *= deform_w[(size_t)c * KK + k];
                g += gc;
            }
        }
        acc += g;
    }

    out[(size_t)b * (HO * WO) + ho * WO + wo] = acc;
}

extern "C" void kernel_launch(void* const* d_in, const int* in_sizes, int n_in,
                              void* d_out, int out_size, void* d_ws, size_t ws_size,
                              hipStream_t stream) {
    const float* x        = (const float*)d_in[0];
    const float* offset_w = (const float*)d_in[1];
    const float* offset_b = (const float*)d_in[2];
    const float* deform_w = (const float*)d_in[3];
    const float* deform_b = (const float*)d_in[4];
    float* out = (float*)d_out;

    if (ws_size >= (size_t)WS_NEED) {
        unsigned char* ws = (unsigned char*)d_ws;
        float* off = (float*)(ws + WS_OFF);
        float* Y   = (float*)(ws + WS_Y);

        hipLaunchKernelGGL(repack_kernel, dim3(1), dim3(256), 0, stream,
                           offset_w, deform_w, ws);
        hipLaunchKernelGGL(convY_kernel, dim3(16, 16, BB), dim3(256), 0, stream,
                           x, offset_b, ws, off, Y);
        hipLaunchKernelGGL(gather_kernel, dim3((NPIX + 255) / 256, BB), dim3(256), 0, stream,
                           off, Y, deform_b, out);
    } else {
        dim3 block(256);
        dim3 grid((WO + TS - 1) / TS, (HO + TS - 1) / TS, BB);
        hipLaunchKernelGGL(deform_fused_fallback, grid, block, 0, stream,
                           x, offset_w, offset_b, deform_w, deform_b, out);
    }
}

// Round 6
// 71.208 us; speedup vs baseline: 7.8208x; 1.1184x over previous
//
#include <hip/hip_runtime.h>
#include <hip/hip_bf16.h>

#define BB 4
#define CC 64
#define HH 256
#define WW 256
#define KK 9
#define NOFF 18
#define HO 254
#define WO 254
#define NPIX (HO*WO)           // 64516
#define TS 16

// ---------------- workspace layout ----------------
#define WS_BC   0
#define WS_DW   25920
#define WS_OFF  32768
#define WS_Y    (WS_OFF + BB*NOFF*NPIX*4)
#define WS_NEED (WS_Y + BB*KK*HH*WW*4)              // 28,050,560

#define SWZ(lin) ((lin) ^ ((((lin) >> 7) & 7) << 4))

typedef __attribute__((ext_vector_type(8))) short bf16x8;
typedef __attribute__((ext_vector_type(4))) float f32x4;

static __device__ __forceinline__ unsigned short f2bf(float v) {
    __hip_bfloat16 h = __float2bfloat16(v);
    union { __hip_bfloat16 b; unsigned short u; } cv; cv.b = h; return cv.u;
}

// ================= kernel W: one-time weight repack =================
__global__ __launch_bounds__(256) void repack_kernel(
    const float* __restrict__ offset_w,
    const float* __restrict__ deform_w,
    unsigned char* __restrict__ ws)
{
    int tid = threadIdx.x;
    for (int i = tid; i < 9 * 20 * 64; i += 256) {
        int tap = i / 1280;
        int rem = i - tap * 1280;
        int o   = rem >> 6;
        int c   = rem & 63;
        float v = (o < NOFF) ? offset_w[((size_t)o * CC + c) * KK + tap] : 0.0f;
        *(unsigned short*)(ws + WS_BC + (size_t)(tap * 20 + o) * 144 + c * 2) = f2bf(v);
    }
    for (int i = tid; i < 16 * 64; i += 256) {
        int tap = i >> 6;
        int c   = i & 63;
        float v = (tap < KK) ? deform_w[(size_t)c * KK + tap] : 0.0f;
        *(unsigned short*)(ws + WS_DW + (size_t)tap * 144 + c * 2) = f2bf(v);
    }
}

// ================= kernel C: offset conv + Y collapse (MFMA) =================
#define PTC 18                 // patch side: TS + 2
#define NCELLC (PTC*PTC)       // 324
#define NITEM  (16*NCELLC)     // 5184 (cpair,cell) items per 32-ch chunk
#define NITER  21              // ceil(5184/256)
#define OFF_SX 0               // 324*64 = 20736
#define OFF_BC 20736           // 25920
#define OFF_DW 46656           // 2304
#define SMEM_C 48960

__global__ __launch_bounds__(256) void convY_kernel(
    const float* __restrict__ x,
    const float* __restrict__ offset_b,
    const unsigned char* __restrict__ ws_w,
    float* __restrict__ off,      // [B][18][NPIX]
    float* __restrict__ Y)        // [B][9][HH*WW]
{
    __shared__ __align__(16) unsigned char smem[SMEM_C];

    const int tid = threadIdx.x;
    const int x0 = blockIdx.x * TS;
    const int y0 = blockIdx.y * TS;
    const int b  = blockIdx.z;
    const float* xb = x + (size_t)b * CC * HH * WW;

    // stage repacked weights (contiguous 28224 B = 1764 x 16B, coalesced)
    {
        const uint4* src = (const uint4*)ws_w;
        uint4* dst = (uint4*)(smem + OFF_BC);
        for (int i = tid; i < 1764; i += 256) dst[i] = src[i];
    }

    // ---- register-batched staging: issue all loads, then commit to LDS ----
    float va[NITER], vb[NITER];

    auto issue_x = [&](int cc0) {
        #pragma unroll
        for (int it = 0; it < NITER; ++it) {
            int i  = tid + it * 256;
            int ii = (i < NITEM) ? i : (NITEM - 1);
            int cpair = ii / NCELLC;
            int cell  = ii - cpair * NCELLC;
            int r   = cell / PTC;
            int col = cell - r * PTC;
            int gy = min(y0 + r, HH - 1);
            int gx = min(x0 + col, WW - 1);
            const float* p = xb + ((size_t)(cc0 + 2 * cpair) * (HH * WW)) + gy * WW + gx;
            va[it] = p[0];
            vb[it] = p[HH * WW];
        }
    };
    auto commit_x = [&]() {
        #pragma unroll
        for (int it = 0; it < NITER; ++it) {
            int i  = tid + it * 256;
            int ii = (i < NITEM) ? i : (NITEM - 1);
            int cpair = ii / NCELLC;
            int cell  = ii - cpair * NCELLC;
            int r   = cell / PTC;
            int col = cell - r * PTC;
            bool inb = (y0 + r < HH) && (x0 + col < WW);
            float v0 = inb ? va[it] : 0.0f;
            float v1 = inb ? vb[it] : 0.0f;
            __hip_bfloat162 h2 = __float22bfloat162_rn(make_float2(v0, v1));
            unsigned int u; __builtin_memcpy(&u, &h2, 4);
            int lin = cell * 64 + cpair * 4;
            if (i < NITEM)
                *(unsigned int*)(smem + OFF_SX + SWZ(lin)) = u;
        }
    };

    const int w  = tid >> 6;
    const int l  = tid & 63;
    const int lr = l & 15;
    const int lk = l >> 4;

    float bias0 = offset_b[lr];
    float bias1 = (lr < 2) ? offset_b[16 + lr] : 0.0f;
    f32x4 accC[4][2];
    #pragma unroll
    for (int mi = 0; mi < 4; ++mi)
        #pragma unroll
        for (int reg = 0; reg < 4; ++reg) { accC[mi][0][reg] = bias0; accC[mi][1][reg] = bias1; }
    f32x4 accY[4];
    #pragma unroll
    for (int mi = 0; mi < 4; ++mi) accY[mi] = (f32x4){0.f, 0.f, 0.f, 0.f};

    auto mfma_half = [&](int cc0) {
        const int o1 = (16 + lr > 19) ? 19 : 16 + lr;
        bf16x8 bY = *(const bf16x8*)(smem + OFF_DW + (size_t)lr * 144 + (cc0 + lk * 8) * 2);
        #pragma unroll
        for (int tap = 0; tap < 9; ++tap) {
            const int kh = tap / 3, kw = tap % 3;
            bf16x8 b0 = *(const bf16x8*)(smem + OFF_BC + (size_t)(tap * 20 + lr) * 144 + (cc0 + lk * 8) * 2);
            bf16x8 b1 = *(const bf16x8*)(smem + OFF_BC + (size_t)(tap * 20 + o1) * 144 + (cc0 + lk * 8) * 2);
            #pragma unroll
            for (int mi = 0; mi < 4; ++mi) {
                int cell = (4 * w + mi + kh) * PTC + (lr + kw);
                bf16x8 a = *(const bf16x8*)(smem + OFF_SX + SWZ(cell * 64 + lk * 16));
                accC[mi][0] = __builtin_amdgcn_mfma_f32_16x16x32_bf16(a, b0, accC[mi][0], 0, 0, 0);
                accC[mi][1] = __builtin_amdgcn_mfma_f32_16x16x32_bf16(a, b1, accC[mi][1], 0, 0, 0);
                if (tap == 0)
                    accY[mi] = __builtin_amdgcn_mfma_f32_16x16x32_bf16(a, bY, accY[mi], 0, 0, 0);
            }
        }
    };

    // ---- pipelined schedule ----
    issue_x(0);
    commit_x();
    __syncthreads();          // chunk0 + weights visible

    issue_x(32);              // chunk1 loads in flight under chunk0 MFMA
    mfma_half(0);
    __syncthreads();          // all waves done reading chunk0

    commit_x();               // waits vmcnt, writes chunk1
    __syncthreads();          // chunk1 visible

    mfma_half(32);

    // ---- store offsets: D col(lr)=o, row(lk*4+reg)=image column ----
    #pragma unroll
    for (int mi = 0; mi < 4; ++mi) {
        int ho = y0 + 4 * w + mi;
        #pragma unroll
        for (int nt = 0; nt < 2; ++nt) {
            int o = nt * 16 + lr;
            if (o < NOFF && ho < HO) {
                float* dst = off + ((size_t)b * NOFF + o) * NPIX + (size_t)ho * WO;
                #pragma unroll
                for (int reg = 0; reg < 4; ++reg) {
                    int wo = x0 + lk * 4 + reg;
                    if (wo < WO) dst[wo] = accC[mi][nt][reg];
                }
            }
        }
        if (lr < KK) {
            float* dst = Y + ((size_t)b * KK + lr) * (HH * WW) + (size_t)(y0 + 4 * w + mi) * WW + x0;
            #pragma unroll
            for (int reg = 0; reg < 4; ++reg)
                dst[lk * 4 + reg] = accY[mi][reg];
        }
    }
}

// ================= kernel G: bilinear gather on collapsed planes =================
__global__ __launch_bounds__(256) void gather_kernel(
    const float* __restrict__ off,     // [B][18][NPIX]
    const float* __restrict__ Y,       // [B][9][HH*WW]
    const float* __restrict__ deform_b,
    float* __restrict__ out)
{
    int p2 = blockIdx.x * 256 + threadIdx.x;
    if (p2 >= NPIX) return;
    int b = blockIdx.y;
    int ho = p2 / WO;
    int wo = p2 - ho * WO;

    const float* offb = off + (size_t)b * NOFF * NPIX;
    const float* Yb   = Y + (size_t)b * KK * (HH * WW);

    float acc = deform_b[0];

    #pragma unroll
    for (int k = 0; k < KK; ++k) {
        const int kh = k / 3, kw = k % 3;
        float dy = offb[(size_t)(2 * k) * NPIX + p2];
        float dx = offb[(size_t)(2 * k + 1) * NPIX + p2];
        float py = (float)(ho + kh) + dy;
        float px = (float)(wo + kw) + dx;
        float y0f = floorf(py), x0f = floorf(px);
        float ly = py - y0f, lx = px - x0f;
        int yi0 = (int)y0f, xi0 = (int)x0f;
        int yi1 = yi0 + 1, xi1 = xi0 + 1;

        float w00 = (1.0f - ly) * (1.0f - lx);
        float w01 = (1.0f - ly) * lx;
        float w10 = ly * (1.0f - lx);
        float w11 = ly * lx;
        if (!(yi0 >= 0 && yi0 < HH && xi0 >= 0 && xi0 < WW)) w00 = 0.0f;
        if (!(yi0 >= 0 && yi0 < HH && xi1 >= 0 && xi1 < WW)) w01 = 0.0f;
        if (!(yi1 >= 0 && yi1 < HH && xi0 >= 0 && xi0 < WW)) w10 = 0.0f;
        if (!(yi1 >= 0 && yi1 < HH && xi1 >= 0 && xi1 < WW)) w11 = 0.0f;

        int y0c = min(max(yi0, 0), HH - 1);
        int y1c = min(max(yi1, 0), HH - 1);
        int x0c = min(max(xi0, 0), WW - 1);
        int x1c = min(max(xi1, 0), WW - 1);

        const float* Yk = Yb + (size_t)k * (HH * WW);
        acc += w00 * Yk[y0c * WW + x0c] + w01 * Yk[y0c * WW + x1c]
             + w10 * Yk[y1c * WW + x0c] + w11 * Yk[y1c * WW + x1c];
    }

    out[(size_t)b * NPIX + p2] = acc;
}

// ================= fallback: fused kernel (used if ws too small) =================
#define S  2
#define PT 22
#define NCELL (PT*PT)
#define FOFF_SX   0
#define FOFF_BC   30976
#define FOFF_DW   56896
#define FSMEM_SZ  59200
#define FOFF_SOFF 0
#define FOFF_SY   18504

__global__ __launch_bounds__(256) void deform_fused_fallback(
    const float* __restrict__ x,
    const float* __restrict__ offset_w,
    const float* __restrict__ offset_b,
    const float* __restrict__ deform_w,
    const float* __restrict__ deform_b,
    float* __restrict__ out)
{
    __shared__ __align__(16) unsigned char smem[FSMEM_SZ];

    const int tid = threadIdx.x;
    const int x0 = blockIdx.x * TS;
    const int y0 = blockIdx.y * TS;
    const int b  = blockIdx.z;
    const float* xb = x + (size_t)b * CC * HH * WW;

    for (int i = tid; i < 9 * 20 * 64; i += 256) {
        int tap = i / 1280;
        int rem = i - tap * 1280;
        int o   = rem >> 6;
        int c   = rem & 63;
        float v = (o < NOFF) ? offset_w[((size_t)o * CC + c) * KK + tap] : 0.0f;
        *(unsigned short*)(smem + FOFF_BC + ((size_t)(tap * 20 + o) * 144 + c * 2)) = f2bf(v);
    }
    for (int i = tid; i < 16 * 64; i += 256) {
        int tap = i >> 6;
        int c   = i & 63;
        float v = (tap < KK) ? deform_w[(size_t)c * KK + tap] : 0.0f;
        *(unsigned short*)(smem + FOFF_DW + (size_t)tap * 144 + c * 2) = f2bf(v);
    }

    auto stage_x = [&](int cc0) {
        for (int i = tid; i < 16 * 512; i += 256) {
            int cpair = i >> 9;
            int cell  = i & 511;
            if (cell >= NCELL) continue;
            int r   = cell / PT;
            int col = cell - r * PT;
            int gy = y0 - S + r;
            int gx = x0 - S + col;
            float v0 = 0.0f, v1 = 0.0f;
            if (gy >= 0 && gy < HH && gx >= 0 && gx < WW) {
                const float* p = xb + (size_t)(cc0 + 2 * cpair) * (HH * WW) + gy * WW + gx;
                v0 = p[0];
                v1 = p[HH * WW];
            }
            __hip_bfloat162 h2 = __float22bfloat162_rn(make_float2(v0, v1));
            unsigned int u; __builtin_memcpy(&u, &h2, 4);
            int lin = cell * 64 + cpair * 4;
            *(unsigned int*)(smem + FOFF_SX + SWZ(lin)) = u;
        }
    };

    stage_x(0);
    __syncthreads();

    const int w  = tid >> 6;
    const int l  = tid & 63;
    const int lr = l & 15;
    const int lk = l >> 4;

    float bias0 = offset_b[lr];
    float bias1 = (lr < 2) ? offset_b[16 + lr] : 0.0f;
    f32x4 accC[4][2];
    #pragma unroll
    for (int mi = 0; mi < 4; ++mi)
        #pragma unroll
        for (int reg = 0; reg < 4; ++reg) { accC[mi][0][reg] = bias0; accC[mi][1][reg] = bias1; }
    f32x4 accY[8];
    #pragma unroll
    for (int yi = 0; yi < 8; ++yi) accY[yi] = (f32x4){0.f, 0.f, 0.f, 0.f};

    #pragma unroll
    for (int half = 0; half < 2; ++half) {
        const int cc0 = half * 32;
        const int koff = lk * 16;

        #pragma unroll
        for (int tap = 0; tap < 9; ++tap) {
            const int kh = tap / 3, kw = tap % 3;
            bf16x8 b0 = *(const bf16x8*)(smem + FOFF_BC + (size_t)(tap * 20 + lr) * 144 + (cc0 + lk * 8) * 2);
            int o1 = 16 + lr; if (o1 > 19) o1 = 19;
            bf16x8 b1 = *(const bf16x8*)(smem + FOFF_BC + (size_t)(tap * 20 + o1) * 144 + (cc0 + lk * 8) * 2);
            #pragma unroll
            for (int mi = 0; mi < 4; ++mi) {
                int row  = 4 * w + mi;
                int cell = (row + kh + S) * PT + (lr + kw + S);
                bf16x8 a = *(const bf16x8*)(smem + FOFF_SX + SWZ(cell * 64 + koff));
                accC[mi][0] = __builtin_amdgcn_mfma_f32_16x16x32_bf16(a, b0, accC[mi][0], 0, 0, 0);
                accC[mi][1] = __builtin_amdgcn_mfma_f32_16x16x32_bf16(a, b1, accC[mi][1], 0, 0, 0);
            }
        }

        bf16x8 bY = *(const bf16x8*)(smem + FOFF_DW + (size_t)lr * 144 + (cc0 + lk * 8) * 2);
        #pragma unroll
        for (int yi = 0; yi < 8; ++yi) {
            int tile = 8 * w + yi;
            if (tile < 31) {
                int cell = tile * 16 + lr; if (cell > NCELL - 1) cell = NCELL - 1;
                bf16x8 a = *(const bf16x8*)(smem + FOFF_SX + SWZ(cell * 64 + koff));
                accY[yi] = __builtin_amdgcn_mfma_f32_16x16x32_bf16(a, bY, accY[yi], 0, 0, 0);
            }
        }

        if (half == 0) {
            __syncthreads();
            stage_x(32);
            __syncthreads();
        }
    }

    __syncthreads();

    float* s_off = (float*)(smem + FOFF_SOFF);
    float* s_Y   = (float*)(smem + FOFF_SY);
    #pragma unroll
    for (int mi = 0; mi < 4; ++mi) {
        #pragma unroll
        for (int nt = 0; nt < 2; ++nt) {
            int o = nt * 16 + lr;
            if (o < NOFF) {
                int pbase = (4 * w + mi) * 16 + lk * 4;
                #pragma unroll
                for (int reg = 0; reg < 4; ++reg)
                    s_off[o * 257 + pbase + reg] = accC[mi][nt][reg];
            }
        }
    }
    #pragma unroll
    for (int yi = 0; yi < 8; ++yi) {
        int tile = 8 * w + yi;
        if (tile < 31 && lr < KK) {
            #pragma unroll
            for (int reg = 0; reg < 4; ++reg) {
                int cell = tile * 16 + lk * 4 + reg;
                if (cell < NCELL) s_Y[lr * 485 + cell] = accY[yi][reg];
            }
        }
    }
    __syncthreads();

    const int ty = tid >> 4, tx = tid & 15;
    const int ho = y0 + ty, wo = x0 + tx;
    if (ho >= HO || wo >= WO) return;

    float acc = deform_b[0];

    #pragma unroll
    for (int k = 0; k < KK; ++k) {
        const int kh = k / 3, kw = k % 3;
        float dy = s_off[(2 * k) * 257 + tid];
        float dx = s_off[(2 * k + 1) * 257 + tid];
        float py = (float)(ho + kh) + dy;
        float px = (float)(wo + kw) + dx;
        float y0f = floorf(py), x0f = floorf(px);
        float ly = py - y0f, lx = px - x0f;
        int yi0 = (int)y0f, xi0 = (int)x0f;
        int ry = yi0 - (y0 - S);
        int rx = xi0 - (x0 - S);
        float w00 = (1.0f - ly) * (1.0f - lx);
        float w01 = (1.0f - ly) * lx;
        float w10 = ly * (1.0f - lx);
        float w11 = ly * lx;
        float g;
        if ((unsigned)ry <= (unsigned)(PT - 2) && (unsigned)rx <= (unsigned)(PT - 2)) {
            const float* tp = s_Y + k * 485;
            int id = ry * PT + rx;
            g = w00 * tp[id]      + w01 * tp[id + 1]
              + w10 * tp[id + PT] + w11 * tp[id + PT + 1];
        } else {
            int yi1 = yi0 + 1, xi1 = xi0 + 1;
            float m00 = (yi0 >= 0 && yi0 < HH && xi0 >= 0 && xi0 < WW) ? w00 : 0.0f;
            float m01 = (yi0 >= 0 && yi0 < HH && xi1 >= 0 && xi1 < WW) ? w01 : 0.0f;
            float m10 = (yi1 >= 0 && yi1 < HH && xi0 >= 0 && xi0 < WW) ? w10 : 0.0f;
            float m11 = (yi1 >= 0 && yi1 < HH && xi1 >= 0 && xi1 < WW) ? w11 : 0.0f;
            int y0cl = min(max(yi0, 0), HH - 1), y1cl = min(max(yi1, 0), HH - 1);
            int x0cl = min(max(xi0, 0), WW - 1), x1cl = min(max(xi1, 0), WW - 1);
            g = 0.0f;
            for (int c = 0; c < CC; ++c) {
                const float* xc = xb + (size_t)c * (HH * WW);
                float gc = m00 * xc[y0cl * WW + x0cl] + m01 * xc[y0cl * WW + x1cl]
                         + m10 * xc[y1cl * WW + x0cl] + m11 * xc[y1cl * WW + x1cl];
                gc *= deform_w[(size_t)c * KK + k];
                g += gc;
            }
        }
        acc += g;
    }

    out[(size_t)b * (HO * WO) + ho * WO + wo] = acc;
}

extern "C" void kernel_launch(void* const* d_in, const int* in_sizes, int n_in,
                              void* d_out, int out_size, void* d_ws, size_t ws_size,
                              hipStream_t stream) {
    const float* x        = (const float*)d_in[0];
    const float* offset_w = (const float*)d_in[1];
    const float* offset_b = (const float*)d_in[2];
    const float* deform_w = (const float*)d_in[3];
    const float* deform_b = (const float*)d_in[4];
    float* out = (float*)d_out;

    if (ws_size >= (size_t)WS_NEED) {
        unsigned char* ws = (unsigned char*)d_ws;
        float* off = (float*)(ws + WS_OFF);
        float* Y   = (float*)(ws + WS_Y);

        hipLaunchKernelGGL(repack_kernel, dim3(1), dim3(256), 0, stream,
                           offset_w, deform_w, ws);
        hipLaunchKernelGGL(convY_kernel, dim3(16, 16, BB), dim3(256), 0, stream,
                           x, offset_b, ws, off, Y);
        hipLaunchKernelGGL(gather_kernel, dim3((NPIX + 255) / 256, BB), dim3(256), 0, stream,
                           off, Y, deform_b, out);
    } else {
        dim3 block(256);
        dim3 grid((WO + TS - 1) / TS, (HO + TS - 1) / TS, BB);
        hipLaunchKernelGGL(deform_fused_fallback, grid, block, 0, stream,
                           x, offset_w, offset_b, deform_w, deform_b, out);
    }
}

// Round 7
// 65.542 us; speedup vs baseline: 8.4969x; 1.0864x over previous
//
#include <hip/hip_runtime.h>
#include <hip/hip_bf16.h>

#define BB 4
#define CC 64
#define HH 256
#define WW 256
#define KK 9
#define NOFF 18
#define HO 254
#define WO 254
#define NPIX (HO*WO)           // 64516

// ---------------- workspace layout ----------------
#define WS_BC   0
#define WS_DW   25920
#define WS_OFF  32768
#define WS_Y    (WS_OFF + BB*NOFF*NPIX*4)
#define WS_NEED (WS_Y + BB*KK*HH*WW*4)              // 28,050,560

#define SWZ(lin) ((lin) ^ ((((lin) >> 7) & 7) << 4))

typedef __attribute__((ext_vector_type(8))) short bf16x8;
typedef __attribute__((ext_vector_type(4))) float f32x4;

static __device__ __forceinline__ unsigned short f2bf(float v) {
    __hip_bfloat16 h = __float2bfloat16(v);
    union { __hip_bfloat16 b; unsigned short u; } cv; cv.b = h; return cv.u;
}

// ================= kernel W: one-time weight repack (10 blocks) =================
__global__ __launch_bounds__(256) void repack_kernel(
    const float* __restrict__ offset_w,
    const float* __restrict__ deform_w,
    unsigned char* __restrict__ ws)
{
    int tid = threadIdx.x;
    int tap = blockIdx.x;
    if (tap < 9) {
        for (int i = tid; i < 20 * 64; i += 256) {
            int o = i >> 6;
            int c = i & 63;
            float v = (o < NOFF) ? offset_w[((size_t)o * CC + c) * KK + tap] : 0.0f;
            *(unsigned short*)(ws + WS_BC + (size_t)(tap * 20 + o) * 144 + c * 2) = f2bf(v);
        }
    } else {
        for (int i = tid; i < 16 * 64; i += 256) {
            int t = i >> 6;
            int c = i & 63;
            float v = (t < KK) ? deform_w[(size_t)c * KK + t] : 0.0f;
            *(unsigned short*)(ws + WS_DW + (size_t)t * 144 + c * 2) = f2bf(v);
        }
    }
}

// ================= kernel C: offset conv + Y collapse (MFMA) =================
#define TSH 8                  // tile rows
#define TSW 16                 // tile cols
#define PTH 10                 // patch rows = TSH + 2
#define PTW 18                 // patch cols = TSW + 2
#define NCELLC (PTH*PTW)       // 180
#define NITEM  (16*NCELLC)     // 2880 (cpair, cell) items per 32-ch chunk
#define NITER  12              // ceil(2880/256)
#define OFF_SX 0               // 180*64 = 11520
#define OFF_BC 11520           // 25920
#define OFF_DW 37440           // 2304
#define SMEM_C 39744

__global__ __launch_bounds__(256) void convY_kernel(
    const float* __restrict__ x,
    const float* __restrict__ offset_b,
    const unsigned char* __restrict__ ws_w,
    float* __restrict__ off,      // [B][18][NPIX]
    float* __restrict__ Y)        // [B][9][HH*WW]
{
    __shared__ __align__(16) unsigned char smem[SMEM_C];

    const int tid = threadIdx.x;
    const int x0 = blockIdx.x * TSW;
    const int y0 = blockIdx.y * TSH;
    const int b  = blockIdx.z;
    const float* xb = x + (size_t)b * CC * HH * WW;

    // stage repacked weights (contiguous 28224 B = 1764 x 16B, coalesced)
    {
        const uint4* src = (const uint4*)ws_w;
        uint4* dst = (uint4*)(smem + OFF_BC);
        for (int i = tid; i < 1764; i += 256) dst[i] = src[i];
    }

    // ---- register-batched staging: issue all loads, then commit to LDS ----
    float va[NITER], vb[NITER];

    auto issue_x = [&](int cc0) {
        #pragma unroll
        for (int it = 0; it < NITER; ++it) {
            int i  = tid + it * 256;
            int ii = (i < NITEM) ? i : (NITEM - 1);
            int cpair = ii / NCELLC;
            int cell  = ii - cpair * NCELLC;
            int r   = cell / PTW;
            int col = cell - r * PTW;
            int gy = min(y0 + r, HH - 1);
            int gx = min(x0 + col, WW - 1);
            const float* p = xb + ((size_t)(cc0 + 2 * cpair) * (HH * WW)) + gy * WW + gx;
            va[it] = p[0];
            vb[it] = p[HH * WW];
        }
    };
    auto commit_x = [&]() {
        #pragma unroll
        for (int it = 0; it < NITER; ++it) {
            int i  = tid + it * 256;
            int ii = (i < NITEM) ? i : (NITEM - 1);
            int cpair = ii / NCELLC;
            int cell  = ii - cpair * NCELLC;
            int r   = cell / PTW;
            int col = cell - r * PTW;
            bool inb = (y0 + r < HH) && (x0 + col < WW);
            float v0 = inb ? va[it] : 0.0f;
            float v1 = inb ? vb[it] : 0.0f;
            __hip_bfloat162 h2 = __float22bfloat162_rn(make_float2(v0, v1));
            unsigned int u; __builtin_memcpy(&u, &h2, 4);
            int lin = cell * 64 + cpair * 4;
            if (i < NITEM)
                *(unsigned int*)(smem + OFF_SX + SWZ(lin)) = u;
        }
    };

    const int w  = tid >> 6;
    const int l  = tid & 63;
    const int lr = l & 15;
    const int lk = l >> 4;

    float bias0 = offset_b[lr];
    float bias1 = (lr < 2) ? offset_b[16 + lr] : 0.0f;
    f32x4 accC[2][2];
    #pragma unroll
    for (int mi = 0; mi < 2; ++mi)
        #pragma unroll
        for (int reg = 0; reg < 4; ++reg) { accC[mi][0][reg] = bias0; accC[mi][1][reg] = bias1; }
    f32x4 accY[2];
    #pragma unroll
    for (int mi = 0; mi < 2; ++mi) accY[mi] = (f32x4){0.f, 0.f, 0.f, 0.f};

    auto mfma_half = [&](int cc0) {
        const int o1 = (16 + lr > 19) ? 19 : 16 + lr;
        bf16x8 bY = *(const bf16x8*)(smem + OFF_DW + (size_t)lr * 144 + (cc0 + lk * 8) * 2);
        #pragma unroll
        for (int tap = 0; tap < 9; ++tap) {
            const int kh = tap / 3, kw = tap % 3;
            bf16x8 b0 = *(const bf16x8*)(smem + OFF_BC + (size_t)(tap * 20 + lr) * 144 + (cc0 + lk * 8) * 2);
            bf16x8 b1 = *(const bf16x8*)(smem + OFF_BC + (size_t)(tap * 20 + o1) * 144 + (cc0 + lk * 8) * 2);
            #pragma unroll
            for (int mi = 0; mi < 2; ++mi) {
                int cell = (2 * w + mi + kh) * PTW + (lr + kw);
                bf16x8 a = *(const bf16x8*)(smem + OFF_SX + SWZ(cell * 64 + lk * 16));
                accC[mi][0] = __builtin_amdgcn_mfma_f32_16x16x32_bf16(a, b0, accC[mi][0], 0, 0, 0);
                accC[mi][1] = __builtin_amdgcn_mfma_f32_16x16x32_bf16(a, b1, accC[mi][1], 0, 0, 0);
                if (tap == 0)
                    accY[mi] = __builtin_amdgcn_mfma_f32_16x16x32_bf16(a, bY, accY[mi], 0, 0, 0);
            }
        }
    };

    // ---- pipelined schedule ----
    issue_x(0);
    commit_x();
    __syncthreads();          // chunk0 + weights visible

    issue_x(32);              // chunk1 loads in flight under chunk0 MFMA
    mfma_half(0);
    __syncthreads();          // all waves done reading chunk0

    commit_x();               // waits vmcnt, writes chunk1
    __syncthreads();          // chunk1 visible

    mfma_half(32);

    // ---- store offsets: D col(lr)=o, D row(lk*4+reg)=image column ----
    #pragma unroll
    for (int mi = 0; mi < 2; ++mi) {
        int ho = y0 + 2 * w + mi;
        #pragma unroll
        for (int nt = 0; nt < 2; ++nt) {
            int o = nt * 16 + lr;
            if (o < NOFF && ho < HO) {
                float* dst = off + ((size_t)b * NOFF + o) * NPIX + (size_t)ho * WO;
                #pragma unroll
                for (int reg = 0; reg < 4; ++reg) {
                    int wo = x0 + lk * 4 + reg;
                    if (wo < WO) dst[wo] = accC[mi][nt][reg];
                }
            }
        }
        // Y rows y0+2w+mi <= 255 always; cols x0..x0+15
        if (lr < KK) {
            float* dst = Y + ((size_t)b * KK + lr) * (HH * WW) + (size_t)(y0 + 2 * w + mi) * WW + x0;
            #pragma unroll
            for (int reg = 0; reg < 4; ++reg)
                dst[lk * 4 + reg] = accY[mi][reg];
        }
    }
}

// ================= kernel G: bilinear gather on collapsed planes =================
__global__ __launch_bounds__(256) void gather_kernel(
    const float* __restrict__ off,     // [B][18][NPIX]
    const float* __restrict__ Y,       // [B][9][HH*WW]
    const float* __restrict__ deform_b,
    float* __restrict__ out)
{
    int p2 = blockIdx.x * 256 + threadIdx.x;
    if (p2 >= NPIX) return;
    int b = blockIdx.y;
    int ho = p2 / WO;
    int wo = p2 - ho * WO;

    const float* offb = off + (size_t)b * NOFF * NPIX;
    const float* Yb   = Y + (size_t)b * KK * (HH * WW);

    float acc = deform_b[0];

    #pragma unroll
    for (int k = 0; k < KK; ++k) {
        const int kh = k / 3, kw = k % 3;
        float dy = offb[(size_t)(2 * k) * NPIX + p2];
        float dx = offb[(size_t)(2 * k + 1) * NPIX + p2];
        float py = (float)(ho + kh) + dy;
        float px = (float)(wo + kw) + dx;
        float y0f = floorf(py), x0f = floorf(px);
        float ly = py - y0f, lx = px - x0f;
        int yi0 = (int)y0f, xi0 = (int)x0f;
        int yi1 = yi0 + 1, xi1 = xi0 + 1;

        float w00 = (1.0f - ly) * (1.0f - lx);
        float w01 = (1.0f - ly) * lx;
        float w10 = ly * (1.0f - lx);
        float w11 = ly * lx;
        if (!(yi0 >= 0 && yi0 < HH && xi0 >= 0 && xi0 < WW)) w00 = 0.0f;
        if (!(yi0 >= 0 && yi0 < HH && xi1 >= 0 && xi1 < WW)) w01 = 0.0f;
        if (!(yi1 >= 0 && yi1 < HH && xi0 >= 0 && xi0 < WW)) w10 = 0.0f;
        if (!(yi1 >= 0 && yi1 < HH && xi1 >= 0 && xi1 < WW)) w11 = 0.0f;

        int y0c = min(max(yi0, 0), HH - 1);
        int y1c = min(max(yi1, 0), HH - 1);
        int x0c = min(max(xi0, 0), WW - 1);
        int x1c = min(max(xi1, 0), WW - 1);

        const float* Yk = Yb + (size_t)k * (HH * WW);
        acc += w00 * Yk[y0c * WW + x0c] + w01 * Yk[y0c * WW + x1c]
             + w10 * Yk[y1c * WW + x0c] + w11 * Yk[y1c * WW + x1c];
    }

    out[(size_t)b * NPIX + p2] = acc;
}

// ================= fallback: fused kernel (used if ws too small) =================
#define TS 16
#define S  2
#define PT 22
#define NCELL (PT*PT)
#define FOFF_SX   0
#define FOFF_BC   30976
#define FOFF_DW   56896
#define FSMEM_SZ  59200
#define FOFF_SOFF 0
#define FOFF_SY   18504

__global__ __launch_bounds__(256) void deform_fused_fallback(
    const float* __restrict__ x,
    const float* __restrict__ offset_w,
    const float* __restrict__ offset_b,
    const float* __restrict__ deform_w,
    const float* __restrict__ deform_b,
    float* __restrict__ out)
{
    __shared__ __align__(16) unsigned char smem[FSMEM_SZ];

    const int tid = threadIdx.x;
    const int x0 = blockIdx.x * TS;
    const int y0 = blockIdx.y * TS;
    const int b  = blockIdx.z;
    const float* xb = x + (size_t)b * CC * HH * WW;

    for (int i = tid; i < 9 * 20 * 64; i += 256) {
        int tap = i / 1280;
        int rem = i - tap * 1280;
        int o   = rem >> 6;
        int c   = rem & 63;
        float v = (o < NOFF) ? offset_w[((size_t)o * CC + c) * KK + tap] : 0.0f;
        *(unsigned short*)(smem + FOFF_BC + ((size_t)(tap * 20 + o) * 144 + c * 2)) = f2bf(v);
    }
    for (int i = tid; i < 16 * 64; i += 256) {
        int tap = i >> 6;
        int c   = i & 63;
        float v = (tap < KK) ? deform_w[(size_t)c * KK + tap] : 0.0f;
        *(unsigned short*)(smem + FOFF_DW + (size_t)tap * 144 + c * 2) = f2bf(v);
    }

    auto stage_x = [&](int cc0) {
        for (int i = tid; i < 16 * 512; i += 256) {
            int cpair = i >> 9;
            int cell  = i & 511;
            if (cell >= NCELL) continue;
            int r   = cell / PT;
            int col = cell - r * PT;
            int gy = y0 - S + r;
            int gx = x0 - S + col;
            float v0 = 0.0f, v1 = 0.0f;
            if (gy >= 0 && gy < HH && gx >= 0 && gx < WW) {
                const float* p = xb + (size_t)(cc0 + 2 * cpair) * (HH * WW) + gy * WW + gx;
                v0 = p[0];
                v1 = p[HH * WW];
            }
            __hip_bfloat162 h2 = __float22bfloat162_rn(make_float2(v0, v1));
            unsigned int u; __builtin_memcpy(&u, &h2, 4);
            int lin = cell * 64 + cpair * 4;
            *(unsigned int*)(smem + FOFF_SX + SWZ(lin)) = u;
        }
    };

    stage_x(0);
    __syncthreads();

    const int w  = tid >> 6;
    const int l  = tid & 63;
    const int lr = l & 15;
    const int lk = l >> 4;

    float bias0 = offset_b[lr];
    float bias1 = (lr < 2) ? offset_b[16 + lr] : 0.0f;
    f32x4 accC[4][2];
    #pragma unroll
    for (int mi = 0; mi < 4; ++mi)
        #pragma unroll
        for (int reg = 0; reg < 4; ++reg) { accC[mi][0][reg] = bias0; accC[mi][1][reg] = bias1; }
    f32x4 accY[8];
    #pragma unroll
    for (int yi = 0; yi < 8; ++yi) accY[yi] = (f32x4){0.f, 0.f, 0.f, 0.f};

    #pragma unroll
    for (int half = 0; half < 2; ++half) {
        const int cc0 = half * 32;
        const int koff = lk * 16;

        #pragma unroll
        for (int tap = 0; tap < 9; ++tap) {
            const int kh = tap / 3, kw = tap % 3;
            bf16x8 b0 = *(const bf16x8*)(smem + FOFF_BC + (size_t)(tap * 20 + lr) * 144 + (cc0 + lk * 8) * 2);
            int o1 = 16 + lr; if (o1 > 19) o1 = 19;
            bf16x8 b1 = *(const bf16x8*)(smem + FOFF_BC + (size_t)(tap * 20 + o1) * 144 + (cc0 + lk * 8) * 2);
            #pragma unroll
            for (int mi = 0; mi < 4; ++mi) {
                int row  = 4 * w + mi;
                int cell = (row + kh + S) * PT + (lr + kw + S);
                bf16x8 a = *(const bf16x8*)(smem + FOFF_SX + SWZ(cell * 64 + koff));
                accC[mi][0] = __builtin_amdgcn_mfma_f32_16x16x32_bf16(a, b0, accC[mi][0], 0, 0, 0);
                accC[mi][1] = __builtin_amdgcn_mfma_f32_16x16x32_bf16(a, b1, accC[mi][1], 0, 0, 0);
            }
        }

        bf16x8 bY = *(const bf16x8*)(smem + FOFF_DW + (size_t)lr * 144 + (cc0 + lk * 8) * 2);
        #pragma unroll
        for (int yi = 0; yi < 8; ++yi) {
            int tile = 8 * w + yi;
            if (tile < 31) {
                int cell = tile * 16 + lr; if (cell > NCELL - 1) cell = NCELL - 1;
                bf16x8 a = *(const bf16x8*)(smem + FOFF_SX + SWZ(cell * 64 + koff));
                accY[yi] = __builtin_amdgcn_mfma_f32_16x16x32_bf16(a, bY, accY[yi], 0, 0, 0);
            }
        }

        if (half == 0) {
            __syncthreads();
            stage_x(32);
            __syncthreads();
        }
    }

    __syncthreads();

    float* s_off = (float*)(smem + FOFF_SOFF);
    float* s_Y   = (float*)(smem + FOFF_SY);
    #pragma unroll
    for (int mi = 0; mi < 4; ++mi) {
        #pragma unroll
        for (int nt = 0; nt < 2; ++nt) {
            int o = nt * 16 + lr;
            if (o < NOFF) {
                int pbase = (4 * w + mi) * 16 + lk * 4;
                #pragma unroll
                for (int reg = 0; reg < 4; ++reg)
                    s_off[o * 257 + pbase + reg] = accC[mi][nt][reg];
            }
        }
    }
    #pragma unroll
    for (int yi = 0; yi < 8; ++yi) {
        int tile = 8 * w + yi;
        if (tile < 31 && lr < KK) {
            #pragma unroll
            for (int reg = 0; reg < 4; ++reg) {
                int cell = tile * 16 + lk * 4 + reg;
                if (cell < NCELL) s_Y[lr * 485 + cell] = accY[yi][reg];
            }
        }
    }
    __syncthreads();

    const int ty = tid >> 4, tx = tid & 15;
    const int ho = y0 + ty, wo = x0 + tx;
    if (ho >= HO || wo >= WO) return;

    float acc = deform_b[0];

    #pragma unroll
    for (int k = 0; k < KK; ++k) {
        const int kh = k / 3, kw = k % 3;
        float dy = s_off[(2 * k) * 257 + tid];
        float dx = s_off[(2 * k + 1) * 257 + tid];
        float py = (float)(ho + kh) + dy;
        float px = (float)(wo + kw) + dx;
        float y0f = floorf(py), x0f = floorf(px);
        float ly = py - y0f, lx = px - x0f;
        int yi0 = (int)y0f, xi0 = (int)x0f;
        int ry = yi0 - (y0 - S);
        int rx = xi0 - (x0 - S);
        float w00 = (1.0f - ly) * (1.0f - lx);
        float w01 = (1.0f - ly) * lx;
        float w10 = ly * (1.0f - lx);
        float w11 = ly * lx;
        float g;
        if ((unsigned)ry <= (unsigned)(PT - 2) && (unsigned)rx <= (unsigned)(PT - 2)) {
            const float* tp = s_Y + k * 485;
            int id = ry * PT + rx;
            g = w00 * tp[id]      + w01 * tp[id + 1]
              + w10 * tp[id + PT] + w11 * tp[id + PT + 1];
        } else {
            int yi1 = yi0 + 1, xi1 = xi0 + 1;
            float m00 = (yi0 >= 0 && yi0 < HH && xi0 >= 0 && xi0 < WW) ? w00 : 0.0f;
            float m01 = (yi0 >= 0 && yi0 < HH && xi1 >= 0 && xi1 < WW) ? w01 : 0.0f;
            float m10 = (yi1 >= 0 && yi1 < HH && xi0 >= 0 && xi0 < WW) ? w10 : 0.0f;
            float m11 = (yi1 >= 0 && yi1 < HH && xi1 >= 0 && xi1 < WW) ? w11 : 0.0f;
            int y0cl = min(max(yi0, 0), HH - 1), y1cl = min(max(yi1, 0), HH - 1);
            int x0cl = min(max(xi0, 0), WW - 1), x1cl = min(max(xi1, 0), WW - 1);
            g = 0.0f;
            for (int c = 0; c < CC; ++c) {
                const float* xc = xb + (size_t)c * (HH * WW);
                float gc = m00 * xc[y0cl * WW + x0cl] + m01 * xc[y0cl * WW + x1cl]
                         + m10 * xc[y1cl * WW + x0cl] + m11 * xc[y1cl * WW + x1cl];
                gc *= deform_w[(size_t)c * KK + k];
                g += gc;
            }
        }
        acc += g;
    }

    out[(size_t)b * (HO * WO) + ho * WO + wo] = acc;
}

extern "C" void kernel_launch(void* const* d_in, const int* in_sizes, int n_in,
                              void* d_out, int out_size, void* d_ws, size_t ws_size,
                              hipStream_t stream) {
    const float* x        = (const float*)d_in[0];
    const float* offset_w = (const float*)d_in[1];
    const float* offset_b = (const float*)d_in[2];
    const float* deform_w = (const float*)d_in[3];
    const float* deform_b = (const float*)d_in[4];
    float* out = (float*)d_out;

    if (ws_size >= (size_t)WS_NEED) {
        unsigned char* ws = (unsigned char*)d_ws;
        float* off = (float*)(ws + WS_OFF);
        float* Y   = (float*)(ws + WS_Y);

        hipLaunchKernelGGL(repack_kernel, dim3(10), dim3(256), 0, stream,
                           offset_w, deform_w, ws);
        hipLaunchKernelGGL(convY_kernel, dim3(16, 32, BB), dim3(256), 0, stream,
                           x, offset_b, ws, off, Y);
        hipLaunchKernelGGL(gather_kernel, dim3((NPIX + 255) / 256, BB), dim3(256), 0, stream,
                           off, Y, deform_b, out);
    } else {
        dim3 block(256);
        dim3 grid((WO + TS - 1) / TS, (HO + TS - 1) / TS, BB);
        hipLaunchKernelGGL(deform_fused_fallback, grid, block, 0, stream,
                           x, offset_w, offset_b, deform_w, deform_b, out);
    }
}